// Round 1
// baseline (518.779 us; speedup 1.0000x reference)
//
#include <hip/hip_runtime.h>

// ConvCaps: fused 3x3 shared conv (votes) + 3-iter dynamic routing.
// B=8, Ci=8, Pi=16, Co=16, Po=16, K=3, H=W=64, pad=1.
// Block = 256 threads, thread t = co*16+po. Each block handles (b, ho, 8 wo).
// Votes kept in registers: acc[ci][p] per thread. Routing via LDS bij/cij +
// 16-lane shuffle reductions (po-groups are 16 consecutive lanes).

namespace {
constexpr int CI = 8, PIn = 16, CO = 16, PO = 16, H = 64, W = 64;
constexpr int TP = 8;           // wo positions per block
constexpr int XSS = 12;         // padded LDS row stride (10 cols used)
}

__global__ __launch_bounds__(256)
void convcaps_fused(const float* __restrict__ x,
                    const float* __restrict__ w,
                    const float* __restrict__ biases,
                    const int* __restrict__ routings_p,
                    float* __restrict__ out)
{
    const int t  = threadIdx.x;        // 0..255
    const int co = t >> 4;
    const int po = t & 15;

    const int blk  = blockIdx.x;       // b*512 + ho*8 + wseg
    const int wseg = blk & 7;
    const int ho   = (blk >> 3) & 63;
    const int b    = blk >> 9;
    const int wo0  = wseg * TP;

    const int routings = routings_p[0];

    __shared__ float xs[CI * PIn * 3 * XSS];   // 4608 f = 18.4 KB
    __shared__ float bb[CI * CO];              // bij  [ci][co]
    __shared__ float cc[CI * CO];              // cij  [ci][co]

    // ---- stage x patch: rows ho-1..ho+1, cols wo0-1..wo0+8, zero-padded ----
    for (int i = t; i < CI * PIn * 3 * XSS; i += 256) {
        int c   = i % XSS;
        int rem = i / XSS;
        int r   = rem % 3;
        int cp  = rem / 3;             // ci*16+pi
        int hy  = ho - 1 + r;
        int wx  = wo0 - 1 + c;
        float v = 0.f;
        if (c < 10 && hy >= 0 && hy < H && wx >= 0 && wx < W)
            v = x[((b * CI * PIn + cp) * H + hy) * W + wx];
        xs[i] = v;
    }
    __syncthreads();

    // ---- conv: votes acc[ci][p] for this thread's oc = t = co*16+po ----
    float acc[CI][TP];
    #pragma unroll
    for (int ci = 0; ci < CI; ++ci)
        #pragma unroll
        for (int p = 0; p < TP; ++p) acc[ci][p] = 0.f;

    for (int pi = 0; pi < PIn; ++pi) {
        float w9[9];
        const float* wp = w + (t * PIn + pi) * 9;   // OIHW: [oc][pi][3][3]
        #pragma unroll
        for (int k = 0; k < 9; ++k) w9[k] = wp[k];

        #pragma unroll
        for (int ci = 0; ci < CI; ++ci) {
            const float* xr = xs + (ci * PIn + pi) * 3 * XSS;
            #pragma unroll
            for (int r = 0; r < 3; ++r) {
                float row[10];
                #pragma unroll
                for (int c2 = 0; c2 < 10; ++c2) row[c2] = xr[r * XSS + c2];
                #pragma unroll
                for (int p = 0; p < TP; ++p)
                    acc[ci][p] += w9[r * 3 + 0] * row[p]
                                + w9[r * 3 + 1] * row[p + 1]
                                + w9[r * 3 + 2] * row[p + 2];
            }
        }
    }

    // ---- routing, one position at a time (votes stay in registers) ----
    const float bias = biases[t];      // [1,1,Co,Po,1,1] flat = [co*16+po]
    float vout[TP];

    for (int p = 0; p < TP; ++p) {
        if (t < CI * CO) bb[t] = 0.f;
        __syncthreads();

        float vj = 0.f;
        for (int it = 0; it < routings; ++it) {
            // softmax over co for each ci: threads 0..127, t = ci*16 + co'
            if (t < CI * CO) {
                float bv = bb[t];
                float m = bv;
                #pragma unroll
                for (int o = 1; o < 16; o <<= 1)
                    m = fmaxf(m, __shfl_xor(m, o, 16));
                float e = __expf(bv - m);
                float s = e;
                #pragma unroll
                for (int o = 1; o < 16; o <<= 1)
                    s += __shfl_xor(s, o, 16);
                cc[t] = e / s;
            }
            __syncthreads();

            // sj = bias + sum_ci cij[ci][co] * votes[ci][co][po]
            float sj = bias;
            #pragma unroll
            for (int ci = 0; ci < CI; ++ci)
                sj += cc[ci * CO + co] * acc[ci][p];

            // squash over po (16 consecutive lanes share co)
            float n2 = sj * sj;
            #pragma unroll
            for (int o = 1; o < 16; o <<= 1)
                n2 += __shfl_xor(n2, o, 16);
            vj = sj * __fsqrt_rn(n2) / (1.f + n2);

            if (it < routings - 1) {
                // bij[ci][co] += sum_po votes[ci][co][po] * vj[co][po]
                #pragma unroll
                for (int ci = 0; ci < CI; ++ci) {
                    float u = acc[ci][p] * vj;
                    #pragma unroll
                    for (int o = 1; o < 16; o <<= 1)
                        u += __shfl_xor(u, o, 16);
                    if (po == 0) bb[ci * CO + co] += u;
                }
                __syncthreads();
            }
        }
        vout[p] = vj;
        __syncthreads();   // protect bb/cc reuse across p iterations
    }

    // ---- write out [B,Co,Po,H,W]: 8 consecutive wo per thread (32B) ----
    float* op = out + (((size_t)(b * CO + co) * PO + po) * H + ho) * W + wo0;
    *reinterpret_cast<float4*>(op)     = make_float4(vout[0], vout[1], vout[2], vout[3]);
    *reinterpret_cast<float4*>(op + 4) = make_float4(vout[4], vout[5], vout[6], vout[7]);
}

extern "C" void kernel_launch(void* const* d_in, const int* in_sizes, int n_in,
                              void* d_out, int out_size, void* d_ws, size_t ws_size,
                              hipStream_t stream) {
    const float* x       = (const float*)d_in[0];
    const float* w       = (const float*)d_in[1];
    const float* biases  = (const float*)d_in[2];
    const int*   routing = (const int*)d_in[3];
    float* out = (float*)d_out;

    dim3 grid(8 * 64 * (64 / TP));   // b * ho * wseg = 4096 blocks
    dim3 block(256);
    hipLaunchKernelGGL(convcaps_fused, grid, block, 0, stream,
                       x, w, biases, routing, out);
}

// Round 3
// 285.234 us; speedup vs baseline: 1.8188x; 1.8188x over previous
//
#include <hip/hip_runtime.h>

// ConvCaps: fused 3x3 shared conv (f16 dot2) + 3-iter dynamic routing.
// B=8, Ci=8, Pi=16, Co=16, Po=16, K=3, H=W=64, pad=1.
// Block = 256 threads, thread t = co*16+po (oc). Each block = (b, ho, 8 wo).
// Conv via v_dot2_f32_f16 over pi-pairs; x staged in LDS transposed to
// [ci][r][q=pi/2][col][pi&1] fp16, 48B-aligned rows -> b128 reads, broadcast.
// Votes in registers acc[ci][p]; routing via LDS bij/cij + 16-lane shuffles.
// XCD-chunked block swizzle keeps the 8 wseg of one (b,ho) on one XCD so
// 32B output runs merge into full 128B lines in a single L2.

namespace {
constexpr int CI = 8, PIn = 16, CO = 16, PO = 16, H = 64, W = 64;
constexpr int TP = 8;          // wo positions per block
constexpr int NQ = 8;          // pi pairs
constexpr int RS = 24;         // halfs per (ci,r,q) row: 20 used + pad -> 48B align
}

typedef __fp16 h2 __attribute__((ext_vector_type(2)));
typedef __fp16 h4 __attribute__((ext_vector_type(4)));
typedef __fp16 h8 __attribute__((ext_vector_type(8)));

__device__ __forceinline__ float dot2f(h2 a, h2 b, float c) {
#if __has_builtin(__builtin_amdgcn_fdot2)
    return __builtin_amdgcn_fdot2(a, b, c, false);
#else
    return fmaf((float)a[0], (float)b[0], fmaf((float)a[1], (float)b[1], c));
#endif
}

__device__ __forceinline__ h2 pkh(float a, float b) {
#if __has_builtin(__builtin_amdgcn_cvt_pkrtz)
    return __builtin_amdgcn_cvt_pkrtz(a, b);
#else
    h2 r; r[0] = (__fp16)a; r[1] = (__fp16)b; return r;
#endif
}

__global__ __launch_bounds__(256)
void convcaps_fused(const float* __restrict__ x,
                    const float* __restrict__ w,
                    const float* __restrict__ biases,
                    const int* __restrict__ routings_p,
                    float* __restrict__ out)
{
    const int t  = threadIdx.x;        // 0..255
    const int co = t >> 4;
    const int po = t & 15;

    // XCD-chunked swizzle: 4096 blocks = 8 XCDs x 512; hw id i -> XCD i%8.
    const int blk  = (blockIdx.x & 7) * 512 + (blockIdx.x >> 3);
    const int wseg = blk & 7;
    const int ho   = (blk >> 3) & 63;
    const int b    = blk >> 9;
    const int wo0  = wseg * TP;

    const int routings = routings_p[0];

    __shared__ __fp16 xs[CI * 3 * NQ * RS];     // 4608 halfs = 9216 B
    __shared__ float bb[CI * CO];               // bij [ci][co]
    __shared__ float cc[CI * CO];               // cij [ci][co]

    // ---- stage x patch, transpose pi to inner pairs, fp32 -> fp16 ----
    // unit u = (ci, r, q, c): loads x[pi=2q] & x[pi=2q+1] at (ho-1+r, wo0-1+c)
    for (int u = t; u < CI * 3 * NQ * 10; u += 256) {
        int c   = u % 10;
        int rem = u / 10;
        int q   = rem % NQ; rem /= NQ;
        int r   = rem % 3;
        int ci  = rem / 3;
        int hy  = ho - 1 + r;
        int wx  = wo0 - 1 + c;
        float f0 = 0.f, f1 = 0.f;
        if (hy >= 0 && hy < H && wx >= 0 && wx < W) {
            const float* xp = x + (((size_t)(b * CI + ci) * PIn + 2 * q) * H + hy) * W + wx;
            f0 = xp[0];
            f1 = xp[H * W];
        }
        *reinterpret_cast<h2*>(&xs[((ci * 3 + r) * NQ + q) * RS + 2 * c]) = pkh(f0, f1);
    }
    __syncthreads();

    // ---- conv: votes acc[ci][p] for this thread's oc = t ----
    float acc[CI][TP];
    #pragma unroll
    for (int ci = 0; ci < CI; ++ci)
        #pragma unroll
        for (int p = 0; p < TP; ++p) acc[ci][p] = 0.f;

    const float* wt = w + t * (PIn * 9);    // OIHW: [oc][pi][3][3]

    #pragma unroll 1
    for (int q = 0; q < NQ; ++q) {
        // weights for pi = 2q, 2q+1: 18 contiguous floats
        float wa[18];
        #pragma unroll
        for (int k = 0; k < 18; ++k) wa[k] = wt[q * 18 + k];
        h2 wq[9];
        #pragma unroll
        for (int k = 0; k < 9; ++k) wq[k] = pkh(wa[k], wa[k + 9]);   // (pi0, pi1)

        #pragma unroll
        for (int ci = 0; ci < CI; ++ci) {
            #pragma unroll
            for (int r = 0; r < 3; ++r) {
                const __fp16* rp = &xs[((ci * 3 + r) * NQ + q) * RS];
                h8 v0 = *reinterpret_cast<const h8*>(rp);
                h8 v1 = *reinterpret_cast<const h8*>(rp + 8);
                h4 v2 = *reinterpret_cast<const h4*>(rp + 16);
                h2 hr[10];
                hr[0] = h2{v0[0], v0[1]}; hr[1] = h2{v0[2], v0[3]};
                hr[2] = h2{v0[4], v0[5]}; hr[3] = h2{v0[6], v0[7]};
                hr[4] = h2{v1[0], v1[1]}; hr[5] = h2{v1[2], v1[3]};
                hr[6] = h2{v1[4], v1[5]}; hr[7] = h2{v1[6], v1[7]};
                hr[8] = h2{v2[0], v2[1]}; hr[9] = h2{v2[2], v2[3]};
                #pragma unroll
                for (int p = 0; p < TP; ++p) {
                    float a = acc[ci][p];
                    a = dot2f(wq[r * 3 + 0], hr[p],     a);
                    a = dot2f(wq[r * 3 + 1], hr[p + 1], a);
                    a = dot2f(wq[r * 3 + 2], hr[p + 2], a);
                    acc[ci][p] = a;
                }
            }
        }
    }

    // ---- routing, one position at a time (votes stay in registers) ----
    const float bias = biases[t];      // [1,1,Co,Po,1,1] flat = [co*16+po]
    float vout[TP];

    #pragma unroll
    for (int p = 0; p < TP; ++p) {
        if (t < CI * CO) bb[t] = 0.f;
        __syncthreads();

        float vj = 0.f;
        for (int it = 0; it < routings; ++it) {
            // softmax over co for each ci: threads 0..127, t = ci*16 + co'
            if (t < CI * CO) {
                float bv = bb[t];
                float m = bv;
                #pragma unroll
                for (int o = 1; o < 16; o <<= 1)
                    m = fmaxf(m, __shfl_xor(m, o, 16));
                float e = __expf(bv - m);
                float s = e;
                #pragma unroll
                for (int o = 1; o < 16; o <<= 1)
                    s += __shfl_xor(s, o, 16);
                cc[t] = e / s;
            }
            __syncthreads();

            // sj = bias + sum_ci cij[ci][co] * votes[ci][co][po]
            float sj = bias;
            #pragma unroll
            for (int ci = 0; ci < CI; ++ci)
                sj += cc[ci * CO + co] * acc[ci][p];

            // squash over po (16 consecutive lanes share co)
            float n2 = sj * sj;
            #pragma unroll
            for (int o = 1; o < 16; o <<= 1)
                n2 += __shfl_xor(n2, o, 16);
            vj = sj * __fsqrt_rn(n2) / (1.f + n2);

            if (it < routings - 1) {
                // bij[ci][co] += sum_po votes[ci][co][po] * vj[co][po]
                #pragma unroll
                for (int ci = 0; ci < CI; ++ci) {
                    float u = acc[ci][p] * vj;
                    #pragma unroll
                    for (int o = 1; o < 16; o <<= 1)
                        u += __shfl_xor(u, o, 16);
                    if (po == 0) bb[ci * CO + co] += u;
                }
                __syncthreads();
            }
        }
        vout[p] = vj;
        __syncthreads();   // protect bb/cc reuse across p iterations
    }

    // ---- write out [B,Co,Po,H,W]: 8 consecutive wo per thread (32B) ----
    float* op = out + (((size_t)(b * CO + co) * PO + po) * H + ho) * W + wo0;
    *reinterpret_cast<float4*>(op)     = make_float4(vout[0], vout[1], vout[2], vout[3]);
    *reinterpret_cast<float4*>(op + 4) = make_float4(vout[4], vout[5], vout[6], vout[7]);
}

extern "C" void kernel_launch(void* const* d_in, const int* in_sizes, int n_in,
                              void* d_out, int out_size, void* d_ws, size_t ws_size,
                              hipStream_t stream) {
    const float* x       = (const float*)d_in[0];
    const float* w       = (const float*)d_in[1];
    const float* biases  = (const float*)d_in[2];
    const int*   routing = (const int*)d_in[3];
    float* out = (float*)d_out;

    dim3 grid(8 * 64 * (64 / TP));   // 4096 blocks = 8 XCD chunks x 512
    dim3 block(256);
    hipLaunchKernelGGL(convcaps_fused, grid, block, 0, stream,
                       x, w, biases, routing, out);
}

// Round 4
// 218.184 us; speedup vs baseline: 2.3777x; 1.3073x over previous
//
#include <hip/hip_runtime.h>

// ConvCaps: fused 3x3 shared conv (f16 dot2) + 3-iter dynamic routing.
// B=8, Ci=8, Pi=16, Co=16, Po=16, K=3, H=W=64, pad=1.
// Block = 256 threads, thread t = co*16+po (oc). Each block = (b, ho, 8 wo).
// Conv via v_dot2_f32_f16; x staged in LDS as [ci][r][q=pi/2][col][pi&1] fp16.
// Routing batched over all 8 pixels per iteration: bb/cc in LDS [p][ci*16+co],
// all 16-lane reductions via DPP row_ror allreduce (VALU, no ds_bpermute),
// 6 barriers per block instead of ~56.
// XCD-chunked block swizzle keeps the 8 wseg of one (b,ho) on one XCD.

namespace {
constexpr int CI = 8, PIn = 16, CO = 16, PO = 16, H = 64, W = 64;
constexpr int TP = 8;          // wo positions per block
constexpr int NQ = 8;          // pi pairs
constexpr int RS = 24;         // halfs per (ci,r,q) row: 20 used + pad
}

typedef __fp16 h2 __attribute__((ext_vector_type(2)));
typedef __fp16 h4 __attribute__((ext_vector_type(4)));
typedef __fp16 h8 __attribute__((ext_vector_type(8)));

__device__ __forceinline__ float dot2f(h2 a, h2 b, float c) {
#if __has_builtin(__builtin_amdgcn_fdot2)
    return __builtin_amdgcn_fdot2(a, b, c, false);
#else
    return fmaf((float)a[0], (float)b[0], fmaf((float)a[1], (float)b[1], c));
#endif
}

__device__ __forceinline__ h2 pkh(float a, float b) {
#if __has_builtin(__builtin_amdgcn_cvt_pkrtz)
    return __builtin_amdgcn_cvt_pkrtz(a, b);
#else
    h2 r; r[0] = (__fp16)a; r[1] = (__fp16)b; return r;
#endif
}

// DPP row-rotate move (within 16-lane row); all call sites are convergent.
template<int CTRL>
__device__ __forceinline__ float dppmovf(float x) {
    return __builtin_bit_cast(float,
        __builtin_amdgcn_mov_dpp(__builtin_bit_cast(int, x), CTRL, 0xf, 0xf, true));
}
// allreduce over the 16-lane row via rotations by 1,2,4,8
__device__ __forceinline__ float rsum16(float x) {
    x += dppmovf<0x121>(x);   // row_ror:1
    x += dppmovf<0x122>(x);   // row_ror:2
    x += dppmovf<0x124>(x);   // row_ror:4
    x += dppmovf<0x128>(x);   // row_ror:8
    return x;
}
__device__ __forceinline__ float rmax16(float x) {
    x = fmaxf(x, dppmovf<0x121>(x));
    x = fmaxf(x, dppmovf<0x122>(x));
    x = fmaxf(x, dppmovf<0x124>(x));
    x = fmaxf(x, dppmovf<0x128>(x));
    return x;
}

__global__ __launch_bounds__(256)
void convcaps_fused(const float* __restrict__ x,
                    const float* __restrict__ w,
                    const float* __restrict__ biases,
                    const int* __restrict__ routings_p,
                    float* __restrict__ out)
{
    const int t  = threadIdx.x;        // 0..255
    const int co = t >> 4;
    const int po = t & 15;

    // XCD-chunked swizzle: 4096 blocks = 8 XCDs x 512; hw id i -> XCD i%8.
    const int blk  = (blockIdx.x & 7) * 512 + (blockIdx.x >> 3);
    const int wseg = blk & 7;
    const int ho   = (blk >> 3) & 63;
    const int b    = blk >> 9;
    const int wo0  = wseg * TP;

    const int routings = routings_p[0];

    __shared__ __fp16 xs[CI * 3 * NQ * RS];     // 4608 halfs = 9216 B
    __shared__ float bb[TP * 128];              // bij [p][ci*16+co]  4 KB
    __shared__ float cc[TP * 128];              // cij [p][ci*16+co]  4 KB

    // ---- stage x patch, transpose pi to inner pairs, fp32 -> fp16 ----
    for (int u = t; u < CI * 3 * NQ * 10; u += 256) {
        int c   = u % 10;
        int rem = u / 10;
        int q   = rem % NQ; rem /= NQ;
        int r   = rem % 3;
        int ci  = rem / 3;
        int hy  = ho - 1 + r;
        int wx  = wo0 - 1 + c;
        float f0 = 0.f, f1 = 0.f;
        if (hy >= 0 && hy < H && wx >= 0 && wx < W) {
            const float* xp = x + (((size_t)(b * CI + ci) * PIn + 2 * q) * H + hy) * W + wx;
            f0 = xp[0];
            f1 = xp[H * W];
        }
        *reinterpret_cast<h2*>(&xs[((ci * 3 + r) * NQ + q) * RS + 2 * c]) = pkh(f0, f1);
    }
    __syncthreads();

    // ---- conv: votes acc[ci][p] for this thread's oc = t ----
    float acc[CI][TP];
    #pragma unroll
    for (int ci = 0; ci < CI; ++ci)
        #pragma unroll
        for (int p = 0; p < TP; ++p) acc[ci][p] = 0.f;

    const float* wt = w + t * (PIn * 9);    // OIHW: [oc][pi][3][3]

    #pragma unroll 1
    for (int q = 0; q < NQ; ++q) {
        float wa[18];
        #pragma unroll
        for (int k = 0; k < 18; ++k) wa[k] = wt[q * 18 + k];
        h2 wq[9];
        #pragma unroll
        for (int k = 0; k < 9; ++k) wq[k] = pkh(wa[k], wa[k + 9]);   // (pi0, pi1)

        #pragma unroll
        for (int ci = 0; ci < CI; ++ci) {
            #pragma unroll
            for (int r = 0; r < 3; ++r) {
                const __fp16* rp = &xs[((ci * 3 + r) * NQ + q) * RS];
                h8 v0 = *reinterpret_cast<const h8*>(rp);
                h8 v1 = *reinterpret_cast<const h8*>(rp + 8);
                h4 v2 = *reinterpret_cast<const h4*>(rp + 16);
                h2 hr[10];
                hr[0] = h2{v0[0], v0[1]}; hr[1] = h2{v0[2], v0[3]};
                hr[2] = h2{v0[4], v0[5]}; hr[3] = h2{v0[6], v0[7]};
                hr[4] = h2{v1[0], v1[1]}; hr[5] = h2{v1[2], v1[3]};
                hr[6] = h2{v1[4], v1[5]}; hr[7] = h2{v1[6], v1[7]};
                hr[8] = h2{v2[0], v2[1]}; hr[9] = h2{v2[2], v2[3]};
                #pragma unroll
                for (int p = 0; p < TP; ++p) {
                    float a = acc[ci][p];
                    a = dot2f(wq[r * 3 + 0], hr[p],     a);
                    a = dot2f(wq[r * 3 + 1], hr[p + 1], a);
                    a = dot2f(wq[r * 3 + 2], hr[p + 2], a);
                    acc[ci][p] = a;
                }
            }
        }
    }

    // ---- routing: all 8 pixels per iteration, DPP reductions ----
    const float bias = biases[t];      // [1,1,Co,Po,1,1] flat = [co*16+po]
    float vj[TP];
    float myu[CI];
    const int  myp = po >> 1;          // pixel this (even-po) lane commits bb for
    const bool wrt = (po & 1) == 0;

    #pragma unroll
    for (int k = 0; k < 4; ++k) bb[t + 256 * k] = 0.f;
    __syncthreads();

    for (int it = 0; it < routings; ++it) {
        // softmax over co for all 1024 (p,ci,co) items; co = low 4 bits -> DPP row
        #pragma unroll
        for (int k = 0; k < 4; ++k) {
            float bv = bb[t + 256 * k];
            float m  = rmax16(bv);
            float e  = __expf(bv - m);
            float s  = rsum16(e);
            cc[t + 256 * k] = e * __builtin_amdgcn_rcpf(s);
        }
        __syncthreads();

        // sj + squash for every pixel; po = 16-lane row -> DPP
        #pragma unroll
        for (int p = 0; p < TP; ++p) {
            float sj = bias;
            #pragma unroll
            for (int ci = 0; ci < CI; ++ci)
                sj += cc[p * 128 + ci * 16 + co] * acc[ci][p];
            float n2 = rsum16(sj * sj);
            vj[p] = sj * __fsqrt_rn(n2) * __builtin_amdgcn_rcpf(1.f + n2);
        }

        if (it < routings - 1) {
            // bij[p][ci][co] += sum_po votes * vj  (allreduce, one writer lane)
            #pragma unroll
            for (int p = 0; p < TP; ++p) {
                #pragma unroll
                for (int ci = 0; ci < CI; ++ci) {
                    float us = rsum16(acc[ci][p] * vj[p]);
                    if (p == myp) myu[ci] = us;
                }
            }
            if (wrt) {
                #pragma unroll
                for (int ci = 0; ci < CI; ++ci)
                    bb[myp * 128 + ci * 16 + co] += myu[ci];
            }
            __syncthreads();
        }
    }

    // ---- write out [B,Co,Po,H,W]: 8 consecutive wo per thread (32B) ----
    float* op = out + (((size_t)(b * CO + co) * PO + po) * H + ho) * W + wo0;
    *reinterpret_cast<float4*>(op)     = make_float4(vj[0], vj[1], vj[2], vj[3]);
    *reinterpret_cast<float4*>(op + 4) = make_float4(vj[4], vj[5], vj[6], vj[7]);
}

extern "C" void kernel_launch(void* const* d_in, const int* in_sizes, int n_in,
                              void* d_out, int out_size, void* d_ws, size_t ws_size,
                              hipStream_t stream) {
    const float* x       = (const float*)d_in[0];
    const float* w       = (const float*)d_in[1];
    const float* biases  = (const float*)d_in[2];
    const int*   routing = (const int*)d_in[3];
    float* out = (float*)d_out;

    dim3 grid(8 * 64 * (64 / TP));   // 4096 blocks = 8 XCD chunks x 512
    dim3 block(256);
    hipLaunchKernelGGL(convcaps_fused, grid, block, 0, stream,
                       x, w, biases, routing, out);
}

// Round 5
// 159.277 us; speedup vs baseline: 3.2571x; 1.3698x over previous
//
#include <hip/hip_runtime.h>

// ConvCaps via MFMA: per block (b, ho, 8 wo), votes = W[256 oc x 144 k] *
// X_im2col[144 k x 64 n], n = p*8+ci, k = (kh*3+kw)*16 + pi (padded to 160).
// mfma_f32_16x16x32_f16, fp32 accumulate. Prep kernel writes fp16 A-frags
// (80 KB) to d_ws once per call; all blocks stream them from L2.
// Routing runs in MFMA C-layout: lane=(p,ci), regs=[co=m][po=g*4+r].
//   ci-sum   : DPP butterfly xor1 (quad_perm 0xB1), xor2 (0x4E), xor7 (0x141)
//   po-sum   : ds_swizzle xor16 (0x401F) + __shfl_xor 32
//   softmax  : 1024 items over 256 threads, DPP row_ror reduces (proven R4)
// Output transposed through LDS (unioned with dead B-tile) -> dense float4.

namespace {
constexpr int CI = 8, PIn = 16, H = 64, Wd = 64;
constexpr int TP = 8;          // wo pixels per block
constexpr int NQ = 8;          // pi pairs in x patch
constexpr int RS = 24;         // halfs per (ci,r,q) patch row (20 used)
constexpr int KT = 5;          // K tiles of 32 (K=160, 144 real)
}

typedef __fp16 h2  __attribute__((ext_vector_type(2)));
typedef __fp16 f16x8 __attribute__((ext_vector_type(8)));
typedef float  f32x4 __attribute__((ext_vector_type(4)));

__device__ __forceinline__ h2 pkh(float a, float b) {
#if __has_builtin(__builtin_amdgcn_cvt_pkrtz)
    return __builtin_amdgcn_cvt_pkrtz(a, b);
#else
    h2 r; r[0] = (__fp16)a; r[1] = (__fp16)b; return r;
#endif
}

template<int CTRL>
__device__ __forceinline__ float dppmovf(float x) {
    return __builtin_bit_cast(float,
        __builtin_amdgcn_mov_dpp(__builtin_bit_cast(int, x), CTRL, 0xf, 0xf, true));
}
template<int CTRL>
__device__ __forceinline__ float dppadd(float x) { return x + dppmovf<CTRL>(x); }

__device__ __forceinline__ float rsum16(float x) {   // over 16-lane row
    x += dppmovf<0x121>(x); x += dppmovf<0x122>(x);
    x += dppmovf<0x124>(x); x += dppmovf<0x128>(x);
    return x;
}
__device__ __forceinline__ float rmax16(float x) {
    x = fmaxf(x, dppmovf<0x121>(x)); x = fmaxf(x, dppmovf<0x122>(x));
    x = fmaxf(x, dppmovf<0x124>(x)); x = fmaxf(x, dppmovf<0x128>(x));
    return x;
}
__device__ __forceinline__ float swz_xor16(float x) {
    return __builtin_bit_cast(float,
        __builtin_amdgcn_ds_swizzle(__builtin_bit_cast(int, x), 0x401F));
}

// ---- prep: conv_w (fp32 OIHW [256][16][3][3]) -> fp16 A-frags in ws ----
// frag f = (kt*16 + m): lane l holds A[oc = m*16 + (l&15)][k = kt*32 + (l>>4)*8 + j]
// k mapping: k = r9*16 + pi, r9 = kh*3+kw; k >= 144 -> 0.
__global__ __launch_bounds__(256)
void prep_wfrag(const float* __restrict__ w, __fp16* __restrict__ wf) {
    const int gid = blockIdx.x * 256 + threadIdx.x;
    if (gid >= KT * 16 * 64) return;
    const int l = gid & 63, m = (gid >> 6) & 15, kt = gid >> 10;
    const int oc = m * 16 + (l & 15);
    h2* dp = reinterpret_cast<h2*>(wf + (size_t)gid * 8);
    #pragma unroll
    for (int jw = 0; jw < 4; ++jw) {
        const int k0 = kt * 32 + (l >> 4) * 8 + jw * 2;
        float f0 = 0.f, f1 = 0.f;
        if (k0 < 144)     f0 = w[oc * 144 + (k0 & 15) * 9 + (k0 >> 4)];
        if (k0 + 1 < 144) f1 = w[oc * 144 + ((k0 + 1) & 15) * 9 + ((k0 + 1) >> 4)];
        dp[jw] = pkh(f0, f1);
    }
}

__global__ __launch_bounds__(256)
void convcaps_mfma(const float* __restrict__ x,
                   const __fp16* __restrict__ wf,
                   const float* __restrict__ biases,
                   const int* __restrict__ routings_p,
                   float* __restrict__ out)
{
    const int t    = threadIdx.x;
    const int lane = t & 63;
    const int wv   = t >> 6;          // wave = ntile
    const int g    = lane >> 4;       // 0..3
    const int nl   = lane & 15;
    const int n    = wv * 16 + nl;    // 0..63 = p*8 + ci
    const int p_   = n >> 3, ci_ = n & 7;

    const int blk  = (blockIdx.x & 7) * 512 + (blockIdx.x >> 3);
    const int wseg = blk & 7;
    const int ho   = (blk >> 3) & 63;
    const int b    = blk >> 9;
    const int wo0  = wseg * TP;
    const int routings = routings_p[0];

    __shared__ __fp16 xs[CI * 3 * NQ * RS];   // 9216 B raw patch
    __shared__ __fp16 Bb[KT * 64 * 32];       // 20480 B im2col B (union: vjlds)
    __shared__ float  bb[64 * 16];            // 4096 B bij [n][co]
    __shared__ float  ccl[64 * 20];           // 5120 B cij [n][co] padded
    __shared__ float  bl[256];                // biases
    float* vjlds = reinterpret_cast<float*>(Bb);   // 256*10 floats after GEMM

    // ---- stage raw x patch (fp32 -> fp16 pairs), biases, bij init ----
    for (int u = t; u < CI * 3 * NQ * 10; u += 256) {
        int c = u % 10, rem = u / 10;
        int q = rem % NQ; rem /= NQ;
        int r = rem % 3, ci = rem / 3;
        int hy = ho - 1 + r, wx = wo0 - 1 + c;
        float f0 = 0.f, f1 = 0.f;
        if (hy >= 0 && hy < H && wx >= 0 && wx < Wd) {
            const float* xp = x + (((size_t)(b * CI + ci) * PIn + 2 * q) * H + hy) * Wd + wx;
            f0 = xp[0]; f1 = xp[H * Wd];
        }
        *reinterpret_cast<h2*>(&xs[((ci * 3 + r) * NQ + q) * RS + 2 * c]) = pkh(f0, f1);
    }
    bl[t] = biases[t];
    #pragma unroll
    for (int k2 = 0; k2 < 4; ++k2) bb[t + 256 * k2] = 0.f;
    __syncthreads();

    // ---- im2col expand: Bb word u = kt*1024 + n*16 + q16; k0 = kt*32+2*q16 ----
    #pragma unroll
    for (int s = 0; s < 20; ++s) {
        const int u   = t + 256 * s;
        const int kt  = u >> 10, rem = u & 1023;
        const int nn  = rem >> 4, q16 = rem & 15;
        const int k0  = kt * 32 + q16 * 2;
        h2 v; v[0] = (__fp16)0.f; v[1] = (__fp16)0.f;
        if (k0 < 144) {
            const int pi = k0 & 15, r9 = k0 >> 4;
            const int kh = r9 / 3, kw = r9 - kh * 3;
            const int c  = (nn >> 3) + kw;            // p + kw in [0,9]
            v = *reinterpret_cast<const h2*>(
                    &xs[(((nn & 7) * 3 + kh) * NQ + (pi >> 1)) * RS + 2 * c]);
        }
        *reinterpret_cast<h2*>(&Bb[u * 2]) = v;
    }
    __syncthreads();

    // ---- GEMM: acc[m] = votes[oc = m*16+g*4+r][n] ----
    f32x4 acc[16];
    #pragma unroll
    for (int m = 0; m < 16; ++m) acc[m] = f32x4{0.f, 0.f, 0.f, 0.f};

    const f16x8* ap = reinterpret_cast<const f16x8*>(wf);
    #pragma unroll
    for (int kt = 0; kt < KT; ++kt) {
        const f16x8 bfrag = *reinterpret_cast<const f16x8*>(
            &Bb[(((kt * 64 + n) * 4) + g) * 8]);
        #pragma unroll
        for (int m = 0; m < 16; ++m) {
            const f16x8 afrag = ap[(kt * 16 + m) * 64 + lane];
            acc[m] = __builtin_amdgcn_mfma_f32_16x16x32_f16(afrag, bfrag, acc[m], 0, 0, 0);
        }
    }

    // ---- routing in MFMA layout ----
    for (int it = 0; it < routings; ++it) {
        // softmax over co: 1024 items, item i -> row=i>>4 (= n), co=i&15
        #pragma unroll
        for (int k2 = 0; k2 < 4; ++k2) {
            const int i   = t + 256 * k2;
            const int row = i >> 4;
            const float bv = bb[i];
            const float mx = rmax16(bv);
            const float e  = __expf(bv - mx);
            const float sd = rsum16(e);
            ccl[row * 20 + (i & 15)] = e * __builtin_amdgcn_rcpf(sd);
        }
        __syncthreads();

        const bool lastit = (it + 1 >= routings);
        #pragma unroll
        for (int m = 0; m < 16; ++m) {
            const float cw = ccl[n * 20 + m];
            float s0 = cw * acc[m][0], s1 = cw * acc[m][1];
            float s2 = cw * acc[m][2], s3 = cw * acc[m][3];
            // sum over ci (lane bits 0..2): xor1, xor2, xor7
            s0 = dppadd<0xB1>(s0);  s1 = dppadd<0xB1>(s1);
            s2 = dppadd<0xB1>(s2);  s3 = dppadd<0xB1>(s3);
            s0 = dppadd<0x4E>(s0);  s1 = dppadd<0x4E>(s1);
            s2 = dppadd<0x4E>(s2);  s3 = dppadd<0x4E>(s3);
            s0 = dppadd<0x141>(s0); s1 = dppadd<0x141>(s1);
            s2 = dppadd<0x141>(s2); s3 = dppadd<0x141>(s3);
            const f32x4 b4 = *reinterpret_cast<const f32x4*>(&bl[m * 16 + g * 4]);
            s0 += b4[0]; s1 += b4[1]; s2 += b4[2]; s3 += b4[3];
            // squash: n2 over po = 4 local r + lanes l^16, l^32
            float q2 = s0 * s0 + s1 * s1 + s2 * s2 + s3 * s3;
            q2 += swz_xor16(q2);
            q2 += __shfl_xor(q2, 32, 64);
            const float sc = __fsqrt_rn(q2) * __builtin_amdgcn_rcpf(1.f + q2);
            const float v0 = s0 * sc, v1 = s1 * sc, v2 = s2 * sc, v3 = s3 * sc;
            if (!lastit) {
                float uu = acc[m][0] * v0 + acc[m][1] * v1
                         + acc[m][2] * v2 + acc[m][3] * v3;
                uu += swz_xor16(uu);
                uu += __shfl_xor(uu, 32, 64);
                if (g == 0) bb[n * 16 + m] += uu;
            } else if (ci_ == 0) {
                const int oc = m * 16 + g * 4;
                vjlds[(oc + 0) * 10 + p_] = v0;
                vjlds[(oc + 1) * 10 + p_] = v1;
                vjlds[(oc + 2) * 10 + p_] = v2;
                vjlds[(oc + 3) * 10 + p_] = v3;
            }
        }
        __syncthreads();
    }

    // ---- dense output: thread t = oc, 8 wo ----
    float o[8];
    #pragma unroll
    for (int j = 0; j < 8; ++j) o[j] = vjlds[t * 10 + j];
    float* op = out + ((size_t)(b * 256 + t)) * (H * Wd) + ho * Wd + wo0;
    *reinterpret_cast<float4*>(op)     = make_float4(o[0], o[1], o[2], o[3]);
    *reinterpret_cast<float4*>(op + 4) = make_float4(o[4], o[5], o[6], o[7]);
}

extern "C" void kernel_launch(void* const* d_in, const int* in_sizes, int n_in,
                              void* d_out, int out_size, void* d_ws, size_t ws_size,
                              hipStream_t stream) {
    const float* x       = (const float*)d_in[0];
    const float* w       = (const float*)d_in[1];
    const float* biases  = (const float*)d_in[2];
    const int*   routing = (const int*)d_in[3];
    float* out = (float*)d_out;
    __fp16* wf = (__fp16*)d_ws;   // needs 81920 B

    hipLaunchKernelGGL(prep_wfrag, dim3(20), dim3(256), 0, stream, w, wf);
    hipLaunchKernelGGL(convcaps_mfma, dim3(8 * 64 * (64 / TP)), dim3(256), 0, stream,
                       x, wf, biases, routing, out);
}